// Round 1
// baseline (87.407 us; speedup 1.0000x reference)
//
#include <hip/hip_runtime.h>
#include <stdint.h>

#define NIN 1024
#define NMID 256
#define NOUT 64

typedef __attribute__((ext_vector_type(8))) short bf16x8;
typedef __attribute__((ext_vector_type(4))) float fx4;

union FragU { bf16x8 v; uint32_t u[4]; };

__device__ __forceinline__ uint32_t cvtpk(float lo, float hi) {
  uint32_t r;
  asm("v_cvt_pk_bf16_f32 %0, %1, %2" : "=v"(r) : "v"(lo), "v"(hi));
  return r;
}

__device__ __forceinline__ void gload16(const void* g, void* l) {
  __builtin_amdgcn_global_load_lds(
      (const __attribute__((address_space(1))) uint32_t*)g,
      (__attribute__((address_space(3))) uint32_t*)l, 16, 0, 0);
}

// ---- kernel 1: convert W1 [256x1024] and W2 [64x256] f32 -> bf16 in ws ----
__global__ __launch_bounds__(256) void cvt_weights(
    const float* __restrict__ W1, const float* __restrict__ W2,
    unsigned short* __restrict__ w1b, unsigned short* __restrict__ w2b) {
  int i = blockIdx.x * 256 + threadIdx.x;
  int e = i << 2;
  const int n1 = NMID * NIN;  // 262144
  if (e < n1) {
    fx4 v = *(const fx4*)(W1 + e);
    uint2 p;
    p.x = cvtpk(v.x, v.y);
    p.y = cvtpk(v.z, v.w);
    *(uint2*)(w1b + e) = p;
  } else {
    int e2 = e - n1;
    if (e2 < NOUT * NMID) {
      fx4 v = *(const fx4*)(W2 + e2);
      uint2 p;
      p.x = cvtpk(v.x, v.y);
      p.y = cvtpk(v.z, v.w);
      *(uint2*)(w2b + e2) = p;
    }
  }
}

// ---- kernel 2: fused 2-layer MLP ----
// block: 256 threads (4 waves). BM=64 rows of batch, BN=256 (full middle), BK=64.
// wave wn computes out cols [64*wn, 64*wn+64) x all 64 rows  (layer 1)
// LDS: xs fp32 [64][64] chunk-XOR swizzled (16KB) + w1s bf16 [256][64] swizzled (32KB)
//      h overlay [64][264] bf16 (33KB) reuses same region after K-loop.
__global__ __launch_bounds__(256) void livenet_main(
    const float* __restrict__ x,
    const unsigned short* __restrict__ w1b,
    const float* __restrict__ b1,
    const unsigned short* __restrict__ w2b,
    const float* __restrict__ b2,
    float* __restrict__ y) {

  __shared__ __align__(16) char smem[49152];

  const int tid = threadIdx.x;
  const int lane = tid & 63;
  const int wn = tid >> 6;       // wave 0..3
  const int l15 = lane & 15;
  const int lg = lane >> 4;      // k-group 0..3
  const int row0 = blockIdx.x * 64;

  // staging source offsets (pre-swizzled global source; LDS dest stays linear)
  // xs: physical chunk pc at (row r) holds logical chunk j = pc ^ (r&15), 16 chunks/row
  uint32_t xoff[4];
#pragma unroll
  for (int i = 0; i < 4; ++i) {
    uint32_t o = (uint32_t)(i * 4096 + tid * 16);
    uint32_t r = o >> 8;
    uint32_t pc = (o >> 4) & 15u;
    uint32_t j = pc ^ (r & 15u);
    xoff[i] = (uint32_t)(row0 + (int)r) * NIN + j * 4u;  // float elems
  }
  // w1s: 8 chunks/row (128B rows), j = pc ^ (r&7)
  uint32_t woff[8];
#pragma unroll
  for (int i = 0; i < 8; ++i) {
    uint32_t o = (uint32_t)(i * 4096 + tid * 16);
    uint32_t r = o >> 7;
    uint32_t pc = (o >> 4) & 7u;
    uint32_t j = pc ^ (r & 7u);
    woff[i] = r * NIN + j * 8u;  // bf16 elems
  }

  fx4 acc[4][4];
#pragma unroll
  for (int i = 0; i < 4; ++i)
#pragma unroll
    for (int j = 0; j < 4; ++j)
      acc[i][j] = (fx4){0.f, 0.f, 0.f, 0.f};

  for (int ks = 0; ks < 16; ++ks) {
    const int k0 = ks * 64;
#pragma unroll
    for (int i = 0; i < 4; ++i)
      gload16(x + xoff[i] + k0, smem + i * 4096 + tid * 16);
#pragma unroll
    for (int i = 0; i < 8; ++i)
      gload16(w1b + woff[i] + k0, smem + 16384 + i * 4096 + tid * 16);
    __syncthreads();  // compiler drains vmcnt(0) before s_barrier

    bf16x8 a[4][2], b[4][2];
    // A frags: read fp32 from swizzled xs, convert to bf16 (RNE cvt_pk)
#pragma unroll
    for (int i = 0; i < 4; ++i) {
      const char* rowp = smem + (16 * i + l15) * 256;  // (16i+l15)&15 == l15
#pragma unroll
      for (int kk = 0; kk < 2; ++kk) {
        uint32_t j = kk * 8 + lg * 2;
        fx4 va = *(const fx4*)(rowp + (uint32_t)((j ^ (uint32_t)l15) << 4));
        fx4 vb = *(const fx4*)(rowp + (uint32_t)(((j + 1) ^ (uint32_t)l15) << 4));
        FragU f;
        f.u[0] = cvtpk(va.x, va.y);
        f.u[1] = cvtpk(va.z, va.w);
        f.u[2] = cvtpk(vb.x, vb.y);
        f.u[3] = cvtpk(vb.z, vb.w);
        a[i][kk] = f.v;
      }
    }
    // B frags: bf16 from swizzled w1s
#pragma unroll
    for (int jn = 0; jn < 4; ++jn) {
      uint32_t rowN = (uint32_t)(wn * 64 + jn * 16 + l15);
      const char* rowp = smem + 16384 + rowN * 128;
#pragma unroll
      for (int kk = 0; kk < 2; ++kk) {
        uint32_t j = (uint32_t)(kk * 4 + lg);
        b[jn][kk] = *(const bf16x8*)(rowp + ((j ^ (rowN & 7u)) << 4));
      }
    }
#pragma unroll
    for (int i = 0; i < 4; ++i)
#pragma unroll
      for (int jn = 0; jn < 4; ++jn)
#pragma unroll
        for (int kk = 0; kk < 2; ++kk)
          acc[i][jn] = __builtin_amdgcn_mfma_f32_16x16x32_bf16(
              a[i][kk], b[jn][kk], acc[i][jn], 0, 0, 0);
    __syncthreads();
  }

  // ---- layer 1 epilogue: bias + relu -> h tile in LDS (bf16, padded rows) ----
  unsigned short* hs = (unsigned short*)smem;  // [64][264]
  float bias1[4];
#pragma unroll
  for (int jn = 0; jn < 4; ++jn) bias1[jn] = b1[wn * 64 + jn * 16 + l15];

#pragma unroll
  for (int i = 0; i < 4; ++i) {
#pragma unroll
    for (int jn = 0; jn < 4; ++jn) {
      int col = wn * 64 + jn * 16 + l15;
#pragma unroll
      for (int rg = 0; rg < 4; ++rg) {
        float v = acc[i][jn][rg] + bias1[jn];
        v = v > 0.f ? v : 0.f;
        int row = i * 16 + lg * 4 + rg;  // C/D layout: col=lane&15, row=(lane>>4)*4+reg
        hs[row * 264 + col] = (unsigned short)cvtpk(v, v);
      }
    }
  }
  __syncthreads();

  // ---- layer 2: y[64][64] = relu(h @ W2^T + b2); wave wn does rows 16*wn..+15 ----
  fx4 acc2[4];
#pragma unroll
  for (int jn = 0; jn < 4; ++jn) acc2[jn] = (fx4){0.f, 0.f, 0.f, 0.f};

#pragma unroll
  for (int ksb = 0; ksb < 8; ++ksb) {
    bf16x8 a2 = *(const bf16x8*)(hs + (wn * 16 + l15) * 264 + ksb * 32 + lg * 8);
#pragma unroll
    for (int jn = 0; jn < 4; ++jn) {
      bf16x8 bw = *(const bf16x8*)(w2b + (jn * 16 + l15) * NMID + ksb * 32 + lg * 8);
      acc2[jn] = __builtin_amdgcn_mfma_f32_16x16x32_bf16(a2, bw, acc2[jn], 0, 0, 0);
    }
  }

  float bias2[4];
#pragma unroll
  for (int jn = 0; jn < 4; ++jn) bias2[jn] = b2[jn * 16 + l15];

#pragma unroll
  for (int jn = 0; jn < 4; ++jn) {
#pragma unroll
    for (int rg = 0; rg < 4; ++rg) {
      float v = acc2[jn][rg] + bias2[jn];
      v = v > 0.f ? v : 0.f;
      int row = row0 + wn * 16 + lg * 4 + rg;
      y[(size_t)row * NOUT + jn * 16 + l15] = v;
    }
  }
}

extern "C" void kernel_launch(void* const* d_in, const int* in_sizes, int n_in,
                              void* d_out, int out_size, void* d_ws, size_t ws_size,
                              hipStream_t stream) {
  const float* x  = (const float*)d_in[0];
  const float* W1 = (const float*)d_in[1];
  const float* b1 = (const float*)d_in[2];
  const float* W2 = (const float*)d_in[3];
  const float* b2 = (const float*)d_in[4];
  float* y = (float*)d_out;

  unsigned short* w1b = (unsigned short*)d_ws;            // 512 KB
  unsigned short* w2b = w1b + (size_t)NMID * NIN;         // +32 KB

  const int batch = in_sizes[0] / NIN;  // 65536

  const int tot4 = (NMID * NIN + NOUT * NMID) / 4;        // 69632
  hipLaunchKernelGGL(cvt_weights, dim3((tot4 + 255) / 256), dim3(256), 0, stream,
                     W1, W2, w1b, w2b);
  hipLaunchKernelGGL(livenet_main, dim3(batch / 64), dim3(256), 0, stream,
                     x, w1b, b1, w2b, b2, y);
}

// Round 2
// 81.859 us; speedup vs baseline: 1.0678x; 1.0678x over previous
//
#include <hip/hip_runtime.h>
#include <stdint.h>

#define NIN 1024
#define NMID 256
#define NOUT 64
#define BM 128
#define BK 64
#define NSTEP (NIN / BK)  // 16

typedef __attribute__((ext_vector_type(8))) short bf16x8;
typedef __attribute__((ext_vector_type(4))) float fx4;
typedef __attribute__((ext_vector_type(16))) float f32x16;
typedef __attribute__((ext_vector_type(4))) uint32_t u32x4;

#define XS_TILE 16384   // 128 rows x 64 bf16 (128B rows, XOR-swizzled chunks)
#define W1_OFF  32768   // xs double buffer ends here
#define W1_TILE 32768   // 256 rows x 64 bf16
#define LDS_SZ  98304   // 32K xs dbuf + 64K w1s dbuf; h[128][256] overlays at 0

__device__ __forceinline__ uint32_t cvtpk(float lo, float hi) {
  uint32_t r;
  asm("v_cvt_pk_bf16_f32 %0, %1, %2" : "=v"(r) : "v"(lo), "v"(hi));
  return r;
}

__device__ __forceinline__ void gload16(const void* g, void* l) {
  __builtin_amdgcn_global_load_lds(
      (const __attribute__((address_space(1))) uint32_t*)g,
      (__attribute__((address_space(3))) uint32_t*)l, 16, 0, 0);
}

// ---- kernel 1: convert W1 [256x1024], W2 [64x256] f32 -> bf16 in ws ----
__global__ __launch_bounds__(256) void cvt_weights(
    const float* __restrict__ W1, const float* __restrict__ W2,
    unsigned short* __restrict__ w1b, unsigned short* __restrict__ w2b) {
  int e = (blockIdx.x * 256 + threadIdx.x) << 2;
  const int n1 = NMID * NIN;
  if (e < n1) {
    fx4 v = *(const fx4*)(W1 + e);
    uint2 p;
    p.x = cvtpk(v.x, v.y);
    p.y = cvtpk(v.z, v.w);
    *(uint2*)(w1b + e) = p;
  } else {
    int e2 = e - n1;
    if (e2 < NOUT * NMID) {
      fx4 v = *(const fx4*)(W2 + e2);
      uint2 p;
      p.x = cvtpk(v.x, v.y);
      p.y = cvtpk(v.z, v.w);
      *(uint2*)(w2b + e2) = p;
    }
  }
}

// ---- kernel 2: fused 2-layer MLP, 512 threads (8 waves, 2M x 4N) ----
// BM=128 batch rows, BN=256 (all mids), BK=64, 32x32x16 MFMA.
// x: global fp32 -> regs -> cvt bf16 -> LDS (XOR-swizzled), double-buffered.
// W1: bf16 via global_load_lds, linear dest + inverse-swizzled source, dbuf.
// One __syncthreads per step; prefetch for t+1 issued before compute of t.
__global__ __launch_bounds__(512, 2) void livenet_main(
    const float* __restrict__ x,
    const unsigned short* __restrict__ w1b,
    const float* __restrict__ b1,
    const unsigned short* __restrict__ w2b,
    const float* __restrict__ b2,
    float* __restrict__ y) {

  extern __shared__ __align__(16) char smem[];

  const int tid = threadIdx.x;
  const int lane = tid & 63;
  const int w = tid >> 6;      // wave 0..7
  const int wm = w >> 2;       // 0..1: row half
  const int wn = w & 3;        // 0..3: col quarter
  const int l31 = lane & 31;
  const int lh = lane >> 5;    // k-half 0/1
  const int row0 = blockIdx.x * BM;

  // x staging: thread -> (row r, 16-float chunk c)
  const int xr_row = tid >> 2;
  const int xr_c = tid & 3;
  const float* xbase = x + (size_t)(row0 + xr_row) * NIN + xr_c * 16;
  const int xrx = xr_row & 7;
  const uint32_t xd0 = (uint32_t)(xr_row * 128 + (((2 * xr_c) ^ xrx) << 4));
  const uint32_t xd1 = (uint32_t)(xr_row * 128 + (((2 * xr_c + 1) ^ xrx) << 4));

  // W1 staging: 4 chunks/thread, linear LDS dest, source inverse-swizzled
  uint32_t w1src[4], w1dst[4];
#pragma unroll
  for (int i = 0; i < 4; ++i) {
    uint32_t o = (uint32_t)(i * 8192 + tid * 16);
    uint32_t r = o >> 7;
    uint32_t pc = (o >> 4) & 7u;
    uint32_t j = pc ^ (r & 7u);
    w1src[i] = r * NIN + j * 8u;  // bf16 elements
    w1dst[i] = o;
  }

  fx4 xl[4];
#define XLOAD(k0)                                     \
  {                                                   \
    const float* p_ = xbase + (k0);                   \
    xl[0] = *(const fx4*)p_;                          \
    xl[1] = *(const fx4*)(p_ + 4);                    \
    xl[2] = *(const fx4*)(p_ + 8);                    \
    xl[3] = *(const fx4*)(p_ + 12);                   \
  }

#define XWRITE(buf)                                                   \
  {                                                                   \
    u32x4 A_ = {cvtpk(xl[0].x, xl[0].y), cvtpk(xl[0].z, xl[0].w),     \
                cvtpk(xl[1].x, xl[1].y), cvtpk(xl[1].z, xl[1].w)};    \
    u32x4 B_ = {cvtpk(xl[2].x, xl[2].y), cvtpk(xl[2].z, xl[2].w),     \
                cvtpk(xl[3].x, xl[3].y), cvtpk(xl[3].z, xl[3].w)};    \
    char* xb_ = smem + (buf) * XS_TILE;                               \
    *(u32x4*)(xb_ + xd0) = A_;                                        \
    *(u32x4*)(xb_ + xd1) = B_;                                        \
  }

#define W1STAGE(buf, k0)                                                      \
  {                                                                           \
    char* wb_ = smem + W1_OFF + (buf) * W1_TILE;                              \
    _Pragma("unroll") for (int i_ = 0; i_ < 4; ++i_)                          \
        gload16(w1b + w1src[i_] + (k0), wb_ + w1dst[i_]);                     \
  }

  f32x16 acc[2][2];
#pragma unroll
  for (int mt = 0; mt < 2; ++mt)
#pragma unroll
    for (int nt = 0; nt < 2; ++nt)
#pragma unroll
      for (int q = 0; q < 16; ++q) acc[mt][nt][q] = 0.f;

  // prologue: stage tile 0
  W1STAGE(0, 0);
  XLOAD(0);
  XWRITE(0);
  __syncthreads();

  // precomputed read offsets
  uint32_t aoff[2], boff[2];
#pragma unroll
  for (int mt = 0; mt < 2; ++mt) {
    uint32_t R = (uint32_t)(wm * 64 + mt * 32 + l31);
    aoff[mt] = R * 128u;  // XOR applied per kk with R&7
  }
#pragma unroll
  for (int nt = 0; nt < 2; ++nt) {
    uint32_t R = (uint32_t)(wn * 64 + nt * 32 + l31);
    boff[nt] = R * 128u;
  }
  const uint32_t arx0 = (uint32_t)((wm * 64 + l31) & 7);
  const uint32_t brx0 = (uint32_t)((wn * 64 + l31) & 7);

  for (int ks = 0; ks < NSTEP; ++ks) {
    const int cur = ks & 1, nxt = cur ^ 1;
    if (ks + 1 < NSTEP) {
      W1STAGE(nxt, (ks + 1) * BK);
      XLOAD((ks + 1) * BK);
    }

    char* xsb = smem + cur * XS_TILE;
    char* w1sb = smem + W1_OFF + cur * W1_TILE;

    bf16x8 a[2][4], b[2][4];
#pragma unroll
    for (int mt = 0; mt < 2; ++mt) {
      uint32_t rx = arx0;  // (wm*64 + mt*32 + l31)&7 == (wm*64+l31)&7
#pragma unroll
      for (int kk = 0; kk < 4; ++kk)
        a[mt][kk] = *(const bf16x8*)(xsb + aoff[mt] +
                                     ((((uint32_t)(kk * 2 + lh)) ^ rx) << 4));
    }
#pragma unroll
    for (int nt = 0; nt < 2; ++nt) {
      uint32_t rx = brx0;
#pragma unroll
      for (int kk = 0; kk < 4; ++kk)
        b[nt][kk] = *(const bf16x8*)(w1sb + boff[nt] +
                                     ((((uint32_t)(kk * 2 + lh)) ^ rx) << 4));
    }

#pragma unroll
    for (int mt = 0; mt < 2; ++mt)
#pragma unroll
      for (int nt = 0; nt < 2; ++nt)
#pragma unroll
        for (int kk = 0; kk < 4; ++kk)
          acc[mt][nt] = __builtin_amdgcn_mfma_f32_32x32x16_bf16(
              a[mt][kk], b[nt][kk], acc[mt][nt], 0, 0, 0);

    if (ks + 1 < NSTEP) XWRITE(nxt);
    __syncthreads();
  }

  // ---- layer-1 epilogue: bias+relu -> h bf16 in LDS [128][256], XOR chunks ----
  float b1v[2];
#pragma unroll
  for (int nt = 0; nt < 2; ++nt) b1v[nt] = b1[wn * 64 + nt * 32 + l31];

#pragma unroll
  for (int mt = 0; mt < 2; ++mt) {
#pragma unroll
    for (int nt = 0; nt < 2; ++nt) {
      int col = wn * 64 + nt * 32 + l31;
#pragma unroll
      for (int rg = 0; rg < 16; ++rg) {
        int row = wm * 64 + mt * 32 + (rg & 3) + 8 * (rg >> 2) + 4 * lh;
        float v = acc[mt][nt][rg] + b1v[nt];
        v = v > 0.f ? v : 0.f;
        int j = (col >> 3) ^ (row & 31);
        *(unsigned short*)(smem + row * 512 + (j << 4) + (col & 7) * 2) =
            (unsigned short)cvtpk(v, v);
      }
    }
  }
  __syncthreads();

  // ---- layer 2: y[128][64] = relu(h @ W2^T + b2), wave w -> (r2, c2) tile ----
  f32x16 acc2;
#pragma unroll
  for (int q = 0; q < 16; ++q) acc2[q] = 0.f;

  const int r2 = (w >> 1) * 32;
  const int c2 = (w & 1) * 32;
  const int arow = r2 + l31;
  const uint32_t arx = (uint32_t)(arow & 31);
  const unsigned short* w2row = w2b + (size_t)(c2 + l31) * NMID + lh * 8;

#pragma unroll
  for (int kk = 0; kk < 16; ++kk) {
    bf16x8 a2 = *(const bf16x8*)(smem + arow * 512 +
                                 ((((uint32_t)(kk * 2 + lh)) ^ arx) << 4));
    bf16x8 bw = *(const bf16x8*)(w2row + kk * 16);
    acc2 = __builtin_amdgcn_mfma_f32_32x32x16_bf16(a2, bw, acc2, 0, 0, 0);
  }

  float bias2 = b2[c2 + l31];
#pragma unroll
  for (int rg = 0; rg < 16; ++rg) {
    int row = r2 + (rg & 3) + 8 * (rg >> 2) + 4 * lh;
    float v = acc2[rg] + bias2;
    v = v > 0.f ? v : 0.f;
    y[(size_t)(row0 + row) * NOUT + c2 + l31] = v;
  }
}

extern "C" void kernel_launch(void* const* d_in, const int* in_sizes, int n_in,
                              void* d_out, int out_size, void* d_ws, size_t ws_size,
                              hipStream_t stream) {
  const float* x  = (const float*)d_in[0];
  const float* W1 = (const float*)d_in[1];
  const float* b1 = (const float*)d_in[2];
  const float* W2 = (const float*)d_in[3];
  const float* b2 = (const float*)d_in[4];
  float* y = (float*)d_out;

  unsigned short* w1b = (unsigned short*)d_ws;
  unsigned short* w2b = w1b + (size_t)NMID * NIN;

  const int batch = in_sizes[0] / NIN;

  const int tot4 = (NMID * NIN + NOUT * NMID) / 4;
  hipLaunchKernelGGL(cvt_weights, dim3((tot4 + 255) / 256), dim3(256), 0, stream,
                     W1, W2, w1b, w2b);

  static int lds_set = 0;
  if (!lds_set) {
    hipFuncSetAttribute((const void*)livenet_main,
                        hipFuncAttributeMaxDynamicSharedMemorySize, LDS_SZ);
    lds_set = 1;
  }
  hipLaunchKernelGGL(livenet_main, dim3(batch / BM), dim3(512), LDS_SZ, stream,
                     x, w1b, b1, w2b, b2, y);
}

// Round 3
// 77.505 us; speedup vs baseline: 1.1278x; 1.0562x over previous
//
#include <hip/hip_runtime.h>
#include <stdint.h>

#define NIN 1024
#define NMID 256
#define NOUT 64
#define BM 128
#define BK 64

typedef __attribute__((ext_vector_type(8))) short bf16x8;
typedef __attribute__((ext_vector_type(4))) float fx4;
typedef __attribute__((ext_vector_type(16))) float f32x16;
typedef __attribute__((ext_vector_type(4))) uint32_t u32x4;

#define XS_TILE 16384   // [128 rows][128B] bf16, XOR-swizzled 16B chunks
#define WOFF    32768   // x double-buffer ends
#define W1_TILE 32768   // [256 rows][128B] bf16, swizzled
#define LDS_SZ  98304   // 2*16K x + 2*32K W1; h[128][256]bf16 (64K) overlays at 0

static __device__ __forceinline__ uint32_t cvtpk(float lo, float hi) {
  uint32_t r;
  asm("v_cvt_pk_bf16_f32 %0, %1, %2" : "=v"(r) : "v"(lo), "v"(hi));
  return r;
}
static __device__ __forceinline__ void gload16(const void* g, void* l) {
  __builtin_amdgcn_global_load_lds(
      (const __attribute__((address_space(1))) uint32_t*)g,
      (__attribute__((address_space(3))) uint32_t*)l, 16, 0, 0);
}

#define VMCNT4() asm volatile("s_waitcnt vmcnt(4)" ::: "memory")
#define VMCNT0() asm volatile("s_waitcnt vmcnt(0)" ::: "memory")
#define LGKM0()  asm volatile("s_waitcnt lgkmcnt(0)" ::: "memory")
#define SBAR()   __builtin_amdgcn_s_barrier()
#define SFENCE() __builtin_amdgcn_sched_barrier(0)

// ---- kernel 1: W1 [256x1024], W2 [64x256] f32 -> bf16 (RNE) in ws ----
__global__ __launch_bounds__(256) void cvt_weights(
    const float* __restrict__ W1, const float* __restrict__ W2,
    unsigned short* __restrict__ w1b, unsigned short* __restrict__ w2b) {
  int e = (blockIdx.x * 256 + threadIdx.x) << 2;
  const int n1 = NMID * NIN;
  if (e < n1) {
    fx4 v = *(const fx4*)(W1 + e);
    uint2 p; p.x = cvtpk(v.x, v.y); p.y = cvtpk(v.z, v.w);
    *(uint2*)(w1b + e) = p;
  } else {
    int e2 = e - n1;
    if (e2 < NOUT * NMID) {
      fx4 v = *(const fx4*)(W2 + e2);
      uint2 p; p.x = cvtpk(v.x, v.y); p.y = cvtpk(v.z, v.w);
      *(uint2*)(w2b + e2) = p;
    }
  }
}

// ---- kernel 2: fused MLP, counted-vmcnt single-barrier pipeline ----
__global__ __launch_bounds__(512, 2) void livenet_main(
    const float* __restrict__ x,
    const unsigned short* __restrict__ w1b,
    const float* __restrict__ b1,
    const unsigned short* __restrict__ w2b,
    const float* __restrict__ b2,
    float* __restrict__ y) {

  extern __shared__ __align__(16) char smem[];

  const int tid = threadIdx.x;
  const int lane = tid & 63;
  const int w = tid >> 6;
  const int wm = w >> 2;
  const int wn = w & 3;
  const int l31 = lane & 31;
  const int lh = lane >> 5;
  const int row0 = blockIdx.x * BM;

  // x staging map: thread -> (row, 16-float chunk)
  const int xr_row = tid >> 2;
  const int xr_c = tid & 3;
  const float* xbase = x + (size_t)(row0 + xr_row) * NIN + xr_c * 16;
  const int xrx = xr_row & 7;
  const uint32_t xd0 = (uint32_t)(xr_row * 128 + (((2 * xr_c) ^ xrx) << 4));
  const uint32_t xd1 = (uint32_t)(xr_row * 128 + (((2 * xr_c + 1) ^ xrx) << 4));

  // W1 staging: linear LDS dest, inverse-swizzled global source
  uint32_t w1src[4], w1dst[4];
#pragma unroll
  for (int i = 0; i < 4; ++i) {
    uint32_t o = (uint32_t)(i * 8192 + tid * 16);
    uint32_t r = o >> 7;
    uint32_t pc = (o >> 4) & 7u;
    uint32_t j = pc ^ (r & 7u);
    w1src[i] = r * NIN + j * 8u;
    w1dst[i] = o;
  }

  fx4 xr[4];
#define XLOAD(k0)                               \
  { const float* p_ = xbase + (k0);             \
    xr[0] = *(const fx4*)p_;                    \
    xr[1] = *(const fx4*)(p_ + 4);              \
    xr[2] = *(const fx4*)(p_ + 8);              \
    xr[3] = *(const fx4*)(p_ + 12); }

#define XWRITE(pbuf)                                                  \
  { u32x4 A_ = {cvtpk(xr[0].x, xr[0].y), cvtpk(xr[0].z, xr[0].w),     \
                cvtpk(xr[1].x, xr[1].y), cvtpk(xr[1].z, xr[1].w)};    \
    u32x4 B_ = {cvtpk(xr[2].x, xr[2].y), cvtpk(xr[2].z, xr[2].w),     \
                cvtpk(xr[3].x, xr[3].y), cvtpk(xr[3].z, xr[3].w)};    \
    char* xb_ = smem + (pbuf) * XS_TILE;                              \
    *(u32x4*)(xb_ + xd0) = A_;                                        \
    *(u32x4*)(xb_ + xd1) = B_; }

#define W1STAGE(pbuf, k0)                                             \
  { char* wb_ = smem + WOFF + (pbuf) * W1_TILE;                       \
    _Pragma("unroll") for (int i_ = 0; i_ < 4; ++i_)                  \
      gload16(w1b + w1src[i_] + (k0), wb_ + w1dst[i_]); }

  f32x16 acc[2][2];
#pragma unroll
  for (int mt = 0; mt < 2; ++mt)
#pragma unroll
    for (int nt = 0; nt < 2; ++nt)
#pragma unroll
      for (int q = 0; q < 16; ++q) acc[mt][nt][q] = 0.f;

  uint32_t aoff[2], boff[2];
#pragma unroll
  for (int mt = 0; mt < 2; ++mt)
    aoff[mt] = (uint32_t)(wm * 64 + mt * 32 + l31) * 128u;
#pragma unroll
  for (int nt = 0; nt < 2; ++nt)
    boff[nt] = (uint32_t)(wn * 64 + nt * 32 + l31) * 128u;
  const uint32_t arx0 = (uint32_t)((wm * 64 + l31) & 7);
  const uint32_t brx0 = (uint32_t)((wn * 64 + l31) & 7);

#define STEP_COMPUTE(xb, wb)                                              \
  { bf16x8 a[2][4], b[2][4];                                              \
    _Pragma("unroll") for (int mt = 0; mt < 2; ++mt)                      \
      _Pragma("unroll") for (int kk = 0; kk < 4; ++kk)                    \
        a[mt][kk] = *(const bf16x8*)((xb) + aoff[mt] +                    \
                     ((((uint32_t)(kk * 2 + lh)) ^ arx0) << 4));          \
    _Pragma("unroll") for (int nt = 0; nt < 2; ++nt)                      \
      _Pragma("unroll") for (int kk = 0; kk < 4; ++kk)                    \
        b[nt][kk] = *(const bf16x8*)((wb) + boff[nt] +                    \
                     ((((uint32_t)(kk * 2 + lh)) ^ brx0) << 4));          \
    __builtin_amdgcn_s_setprio(1);                                        \
    _Pragma("unroll") for (int mt = 0; mt < 2; ++mt)                      \
      _Pragma("unroll") for (int nt = 0; nt < 2; ++nt)                    \
        _Pragma("unroll") for (int kk = 0; kk < 4; ++kk)                  \
          acc[mt][nt] = __builtin_amdgcn_mfma_f32_32x32x16_bf16(          \
              a[mt][kk], b[nt][kk], acc[mt][nt], 0, 0, 0);                \
    __builtin_amdgcn_s_setprio(0); }

  // ---- prologue: queue = [x0, W1(0)] -> consume x0 -> queue [x1] ----
  XLOAD(0);            // +4 vmem (x0)
  W1STAGE(0, 0);       // +4 vmem (W1_0)
  VMCNT4();            // x0 regs arrived (W1_0 still flying)
  SFENCE();
  XWRITE(0);           // cvt + ds_write x0 -> xbuf[0]
  XLOAD(BK);           // +4 vmem (x1); queue [W1_0, x1]
  VMCNT4();            // W1_0 DMA landed (x1 flying)
  LGKM0();
  SBAR();              // all waves: tile 0 fully in LDS
  SFENCE();

  // ---- steady iters t=0..13 (invariant entering: queue = [x(t+1)]) ----
  for (int t = 0; t < 14; ++t) {
    const int pc = t & 1, pn = pc ^ 1;
    char* xb = smem + pc * XS_TILE;
    char* wb = smem + WOFF + pc * W1_TILE;
    W1STAGE(pn, (t + 1) * BK);   // queue [x(t+1), W1(t+1)]
    STEP_COMPUTE(xb, wb);        // tile t
    VMCNT4();                    // x(t+1) regs arrived
    SFENCE();
    XWRITE(pn);                  // x(t+1) -> xbuf[pn]
    XLOAD((t + 2) * BK);         // queue [W1(t+1), x(t+2)]
    VMCNT4();                    // W1(t+1) landed (x(t+2) flying)
    LGKM0();                     // x-writes visible
    SBAR();
    SFENCE();
  }

  // ---- t=14 (no x(16) issue) ----
  {
    char* xb = smem + 0 * XS_TILE;      // pc=0
    char* wb = smem + WOFF + 0 * W1_TILE;
    W1STAGE(1, 15 * BK);         // queue [x15, W1_15]
    STEP_COMPUTE(xb, wb);
    VMCNT4();                    // x15 arrived
    SFENCE();
    XWRITE(1);
    VMCNT0();                    // W1_15 landed; queue empty
    LGKM0();
    SBAR();
    SFENCE();
  }
  // ---- t=15 ----
  {
    char* xb = smem + 1 * XS_TILE;
    char* wb = smem + WOFF + 1 * W1_TILE;
    STEP_COMPUTE(xb, wb);
  }
  __syncthreads();  // reads drained before h overlays staging LDS

  // ---- layer-1 epilogue: bias+relu -> h bf16 [128][256] (32-chunk XOR) ----
  float b1v[2];
#pragma unroll
  for (int nt = 0; nt < 2; ++nt) b1v[nt] = b1[wn * 64 + nt * 32 + l31];

#pragma unroll
  for (int mt = 0; mt < 2; ++mt) {
#pragma unroll
    for (int nt = 0; nt < 2; ++nt) {
      int col = wn * 64 + nt * 32 + l31;
#pragma unroll
      for (int rg = 0; rg < 16; ++rg) {
        int row = wm * 64 + mt * 32 + (rg & 3) + 8 * (rg >> 2) + 4 * lh;
        float v = acc[mt][nt][rg] + b1v[nt];
        v = v > 0.f ? v : 0.f;
        int j = (col >> 3) ^ (row & 31);
        *(unsigned short*)(smem + row * 512 + (j << 4) + (col & 7) * 2) =
            (unsigned short)cvtpk(v, v);
      }
    }
  }
  __syncthreads();

  // ---- layer 2: y = relu(h @ W2^T + b2) ----
  f32x16 acc2;
#pragma unroll
  for (int q = 0; q < 16; ++q) acc2[q] = 0.f;

  const int r2 = (w >> 1) * 32;
  const int c2 = (w & 1) * 32;
  const int arow = r2 + l31;
  const uint32_t arx = (uint32_t)(arow & 31);
  const unsigned short* w2row = w2b + (size_t)(c2 + l31) * NMID + lh * 8;

#pragma unroll
  for (int kk = 0; kk < 16; ++kk) {
    bf16x8 a2 = *(const bf16x8*)(smem + arow * 512 +
                                 ((((uint32_t)(kk * 2 + lh)) ^ arx) << 4));
    bf16x8 bw = *(const bf16x8*)(w2row + kk * 16);
    acc2 = __builtin_amdgcn_mfma_f32_32x32x16_bf16(a2, bw, acc2, 0, 0, 0);
  }

  float bias2 = b2[c2 + l31];
#pragma unroll
  for (int rg = 0; rg < 16; ++rg) {
    int row = r2 + (rg & 3) + 8 * (rg >> 2) + 4 * lh;
    float v = acc2[rg] + bias2;
    v = v > 0.f ? v : 0.f;
    y[(size_t)(row0 + row) * NOUT + c2 + l31] = v;
  }
}

extern "C" void kernel_launch(void* const* d_in, const int* in_sizes, int n_in,
                              void* d_out, int out_size, void* d_ws, size_t ws_size,
                              hipStream_t stream) {
  const float* x  = (const float*)d_in[0];
  const float* W1 = (const float*)d_in[1];
  const float* b1 = (const float*)d_in[2];
  const float* W2 = (const float*)d_in[3];
  const float* b2 = (const float*)d_in[4];
  float* y = (float*)d_out;

  unsigned short* w1b = (unsigned short*)d_ws;
  unsigned short* w2b = w1b + (size_t)NMID * NIN;

  const int batch = in_sizes[0] / NIN;

  const int tot4 = (NMID * NIN + NOUT * NMID) / 4;
  hipLaunchKernelGGL(cvt_weights, dim3((tot4 + 255) / 256), dim3(256), 0, stream,
                     W1, W2, w1b, w2b);

  static int lds_set = 0;
  if (!lds_set) {
    hipFuncSetAttribute((const void*)livenet_main,
                        hipFuncAttributeMaxDynamicSharedMemorySize, LDS_SZ);
    lds_set = 1;
  }
  hipLaunchKernelGGL(livenet_main, dim3(batch / BM), dim3(512), LDS_SZ, stream,
                     x, w1b, b1, w2b, b2, y);
}